// Round 7
// baseline (298.861 us; speedup 1.0000x reference)
//
#include <hip/hip_runtime.h>
#include <math.h>

#define NUM_K   1024
#define CDIM    64
#define HW      1024          // 32*32
#define NROWS   65536         // 64*1024
#define NBLK    1024          // epilogue blocks (64 rows each)
#define APAD    200           // A_s row stride in bf16 elems (400 B = 25*16B, odd -> bank-balanced)
#define BPAD    224           // esp row stride in bf16 elems (448 B, 64B-aligned fragments)
#define EPS_THR 1.25e-4f      // candidate threshold on packed g~ (incl. pack granularity)
#define XPAD    65            // rescan x_s row pad: (lane*65+c)%32 spreads banks (2/bank = free)

using bf16x8 = __attribute__((ext_vector_type(8))) short;
using f32x4  = __attribute__((ext_vector_type(4))) float;

// numpy pairwise_sum order for n=64 contiguous fp32 (8 stride-8 chains,
// ((r0+r1)+(r2+r3))+((r4+r5)+(r6+r7))), squares rounded separately (no FMA).
__device__ __forceinline__ float np_sumsq64(const float* a) {
#pragma clang fp contract(off)
  float r0 = a[0]*a[0], r1 = a[1]*a[1], r2 = a[2]*a[2], r3 = a[3]*a[3];
  float r4 = a[4]*a[4], r5 = a[5]*a[5], r6 = a[6]*a[6], r7 = a[7]*a[7];
#pragma unroll
  for (int i = 8; i < 64; i += 8) {
    r0 += a[i+0]*a[i+0]; r1 += a[i+1]*a[i+1];
    r2 += a[i+2]*a[i+2]; r3 += a[i+3]*a[i+3];
    r4 += a[i+4]*a[i+4]; r5 += a[i+5]*a[i+5];
    r6 += a[i+6]*a[i+6]; r7 += a[i+7]*a[i+7];
  }
  return ((r0+r1)+(r2+r3))+((r4+r5)+(r6+r7));
}

// Pass 0: exact norms + split codebook e' = [e_hi | e_hi | e_lo] (bf16 trunc split).
__global__ void vq_prep(const float* __restrict__ emb, float* __restrict__ norms,
                        unsigned short* __restrict__ esp)
{
  const int k = blockIdx.x * blockDim.x + threadIdx.x;
  if (k >= NUM_K) return;
  norms[k] = np_sumsq64(emb + k * CDIM);
  unsigned short* row = esp + (size_t)k * BPAD;
  for (int c = 0; c < CDIM; ++c) {
    const float v = emb[k * CDIM + c];
    const unsigned int vb = __float_as_uint(v);
    const unsigned short h = (unsigned short)(vb >> 16);           // bf16 trunc
    const float res = v - __uint_as_float((unsigned int)h << 16);
    const unsigned short l = (unsigned short)(__float_as_uint(res) >> 16);
    row[c] = h; row[64 + c] = h; row[128 + c] = l;
  }
  for (int i = 192; i < BPAD; ++i) row[i] = 0;
}

// Pass 1: split-bf16 MFMA distance filter (validated r1-r6, absmax 0). Unchanged.
__global__ __launch_bounds__(256, 2)
void vq_dist(const float* __restrict__ xin, const float* __restrict__ norms,
             const unsigned short* __restrict__ esp, float* __restrict__ out_idx,
             unsigned int* __restrict__ nflag, unsigned int* __restrict__ flaglist)
{
  __shared__ __align__(16) unsigned short A_s[64 * APAD];   // 25600 B
  __shared__ float red_m1[4][64];
  __shared__ float red_m2[4][64];

  const int t    = threadIdx.x;
  const int lane = t & 63;
  const int w    = t >> 6;        // wave id = 32-col slice of each 128-col chunk
  const int l15  = lane & 15;
  const int g4   = lane >> 4;

  const int n0  = blockIdx.x * 64;
  const int b   = n0 >> 10;
  const int hw0 = n0 & (HW - 1);

  // ---- stage A: load x (coalesced across rows), trunc-split, pack [hi|lo|hi] ----
  {
    const int r = t & 63, q = t >> 6;             // row, 16-channel quarter
    const float* xb = xin + (size_t)b * (CDIM * HW) + hw0 + r;
    unsigned short* arow = A_s + r * APAD;
#pragma unroll
    for (int u = 0; u < 8; ++u) {
      const int c0 = q * 16 + 2 * u;
      const float v0 = xb[(size_t)c0 * HW];
      const float v1 = xb[(size_t)(c0 + 1) * HW];
      const unsigned int h0 = __float_as_uint(v0) >> 16;
      const unsigned int h1 = __float_as_uint(v1) >> 16;
      const float r0 = v0 - __uint_as_float(h0 << 16);
      const float r1 = v1 - __uint_as_float(h1 << 16);
      const unsigned int lo0 = __float_as_uint(r0) >> 16;
      const unsigned int lo1 = __float_as_uint(r1) >> 16;
      const unsigned int hh = h0 | (h1 << 16);
      const unsigned int ll = lo0 | (lo1 << 16);
      *(unsigned int*)(arow + c0)        = hh;   // slots [0,64):   x_hi
      *(unsigned int*)(arow + 64 + c0)   = ll;   // slots [64,128): x_lo
      *(unsigned int*)(arow + 128 + c0)  = hh;   // slots [128,192):x_hi
    }
  }
  __syncthreads();

  float m1[16], m2[16];
#pragma unroll
  for (int i = 0; i < 16; ++i) { m1[i] = INFINITY; m2[i] = INFINITY; }

  // per-lane A fragment base (bf16 elems); rt adds 16*APAD, s adds 32
  const unsigned short* aF = A_s + l15 * APAD + g4 * 8;
  // per-lane B pointers for (ct0, ct1); s adds 32, chunk adds 128*BPAD
  const unsigned short* pB = esp + (size_t)(w * 32 + l15) * BPAD + g4 * 8;
  const float* pN = norms + w * 32 + l15;

  // preloaded s=0 fragments of the current chunk (carried across iterations;
  // last iteration's extra preload reads harmless in-bounds garbage past esp)
  bf16x8 c0 = *(const bf16x8*)(pB);
  bf16x8 c1 = *(const bf16x8*)(pB + 16 * BPAD);

#pragma unroll 1
  for (int cb = 0; cb < 8; ++cb) {
    const float nk0 = pN[0];
    const float nk1 = pN[16];

    f32x4 acc[4][2];
#pragma unroll
    for (int rt = 0; rt < 4; ++rt)
#pragma unroll
      for (int ct = 0; ct < 2; ++ct)
        acc[rt][ct] = (f32x4){0.0f, 0.0f, 0.0f, 0.0f};

    // s = 0 uses the preloaded pair
    {
      const bf16x8 a0 = *(const bf16x8*)(aF);
      const bf16x8 a1 = *(const bf16x8*)(aF + 16 * APAD);
      const bf16x8 a2 = *(const bf16x8*)(aF + 32 * APAD);
      const bf16x8 a3 = *(const bf16x8*)(aF + 48 * APAD);
      acc[0][0] = __builtin_amdgcn_mfma_f32_16x16x32_bf16(a0, c0, acc[0][0], 0, 0, 0);
      acc[1][0] = __builtin_amdgcn_mfma_f32_16x16x32_bf16(a1, c0, acc[1][0], 0, 0, 0);
      acc[2][0] = __builtin_amdgcn_mfma_f32_16x16x32_bf16(a2, c0, acc[2][0], 0, 0, 0);
      acc[3][0] = __builtin_amdgcn_mfma_f32_16x16x32_bf16(a3, c0, acc[3][0], 0, 0, 0);
      acc[0][1] = __builtin_amdgcn_mfma_f32_16x16x32_bf16(a0, c1, acc[0][1], 0, 0, 0);
      acc[1][1] = __builtin_amdgcn_mfma_f32_16x16x32_bf16(a1, c1, acc[1][1], 0, 0, 0);
      acc[2][1] = __builtin_amdgcn_mfma_f32_16x16x32_bf16(a2, c1, acc[2][1], 0, 0, 0);
      acc[3][1] = __builtin_amdgcn_mfma_f32_16x16x32_bf16(a3, c1, acc[3][1], 0, 0, 0);
    }
#pragma unroll
    for (int s = 1; s < 6; ++s) {
      const bf16x8 b0 = *(const bf16x8*)(pB + s * 32);
      const bf16x8 b1 = *(const bf16x8*)(pB + 16 * BPAD + s * 32);
      const bf16x8 a0 = *(const bf16x8*)(aF + s * 32);
      const bf16x8 a1 = *(const bf16x8*)(aF + 16 * APAD + s * 32);
      const bf16x8 a2 = *(const bf16x8*)(aF + 32 * APAD + s * 32);
      const bf16x8 a3 = *(const bf16x8*)(aF + 48 * APAD + s * 32);
      acc[0][0] = __builtin_amdgcn_mfma_f32_16x16x32_bf16(a0, b0, acc[0][0], 0, 0, 0);
      acc[1][0] = __builtin_amdgcn_mfma_f32_16x16x32_bf16(a1, b0, acc[1][0], 0, 0, 0);
      acc[2][0] = __builtin_amdgcn_mfma_f32_16x16x32_bf16(a2, b0, acc[2][0], 0, 0, 0);
      acc[3][0] = __builtin_amdgcn_mfma_f32_16x16x32_bf16(a3, b0, acc[3][0], 0, 0, 0);
      acc[0][1] = __builtin_amdgcn_mfma_f32_16x16x32_bf16(a0, b1, acc[0][1], 0, 0, 0);
      acc[1][1] = __builtin_amdgcn_mfma_f32_16x16x32_bf16(a1, b1, acc[1][1], 0, 0, 0);
      acc[2][1] = __builtin_amdgcn_mfma_f32_16x16x32_bf16(a2, b1, acc[2][1], 0, 0, 0);
      acc[3][1] = __builtin_amdgcn_mfma_f32_16x16x32_bf16(a3, b1, acc[3][1], 0, 0, 0);
    }

    const unsigned kbase = (unsigned)(cb * 128 + w * 32 + l15);
    pB += 128 * BPAD;
    pN += 128;
    // preload next chunk's s=0 pair; hides L2 latency under the epilogue VALU
    c0 = *(const bf16x8*)(pB);
    c1 = *(const bf16x8*)(pB + 16 * BPAD);

    // epilogue: g~ = nk - 2*dot~, pack col idx into low 10 mantissa bits, fminf-track.
#pragma unroll
    for (int ct = 0; ct < 2; ++ct) {
      const float nk = ct ? nk1 : nk0;
      const unsigned kcol = kbase + (unsigned)(ct * 16);
#pragma unroll
      for (int rt = 0; rt < 4; ++rt) {
#pragma unroll
        for (int rg = 0; rg < 4; ++rg) {
          const float g  = fmaf(-2.0f, acc[rt][ct][rg], nk);
          const float gp = __uint_as_float((__float_as_uint(g) & 0xFFFFFC00u) | kcol);
          const int   si = rt * 4 + rg;
          m2[si] = fminf(m2[si], fmaxf(m1[si], gp));
          m1[si] = fminf(m1[si], gp);
        }
      }
    }
  }

  // butterfly merge across the 16 col-lanes (packed: no index shuffles needed)
#pragma unroll
  for (int mask = 1; mask <= 8; mask <<= 1) {
#pragma unroll
    for (int si = 0; si < 16; ++si) {
      const float om1 = __shfl_xor(m1[si], mask, 64);
      const float om2 = __shfl_xor(m2[si], mask, 64);
      m2[si] = fminf(fminf(m2[si], om2), fmaxf(m1[si], om1));
      m1[si] = fminf(m1[si], om1);
    }
  }
  if (l15 == 0) {
#pragma unroll
    for (int rt = 0; rt < 4; ++rt)
#pragma unroll
      for (int rg = 0; rg < 4; ++rg) {
        const int row = rt * 16 + g4 * 4 + rg;
        red_m1[w][row] = m1[rt * 4 + rg];
        red_m2[w][row] = m2[rt * 4 + rg];
      }
  }
  __syncthreads();
  if (t < 64) {
    float M1 = red_m1[0][t], M2 = red_m2[0][t];
#pragma unroll
    for (int ww = 1; ww < 4; ++ww) {
      const float om1 = red_m1[ww][t], om2 = red_m2[ww][t];
      M2 = fminf(fminf(M2, om2), fmaxf(M1, om1));
      M1 = fminf(M1, om1);
    }
    const int K1 = (int)(__float_as_uint(M1) & 1023u);
    out_idx[n0 + t] = (float)K1;     // best guess; flagged rows fixed by rescan
    if (M2 - M1 <= EPS_THR) {        // gap too small -> exact rescan required
      const unsigned pos = atomicAdd(nflag, 1u);
      flaglist[pos] = (unsigned)(n0 + t);
    }
  }
}

// Pass 2b: exact rescan v5 — lane=row, wave-uniform code stream (r7 rewrite).
// Root cause of r5/r6's fixed ~115us: per-lane private code streams serialize on
// L2 latency (xr[64] leaves no VGPRs to pipeline 32 loads/iter). Inversion: each
// LANE owns one flagged row; the WAVE scans the SAME code k -> e-loads are
// wave-uniform (TA coalesces 64 identical addrs to ~1 line/instr) and the 64
// lanes provide free cross-row ILP. Dual-code chains (d0,d1) fill the 4-cy FMA
// latency slots -> issue-bound, not latency-bound.
// Block = 512 thr (8 waves) = 64 rows; x staged once to LDS ([64][65] pad ->
// conflict-free), wave w scans chunk [w*128, w*128+128). Winner per (row,chunk)
// written non-atomically to pmin[ridx*8+w] as the validated monotone u64 pack.
// Exact chain semantics unchanged: same serial FMA order, same q=(S-2d)+nk,
// strict < over ascending k; chunk merge via u64 min = lex (d,k) first-min.
__global__ __launch_bounds__(512)
void vq_rescan(const float* __restrict__ xin, const float* __restrict__ emb,
               const float* __restrict__ norms,
               const unsigned int* __restrict__ nflag,
               const unsigned int* __restrict__ flaglist,
               unsigned long long* __restrict__ pmin)
{
  __shared__ float x_s[64 * XPAD];   // 16.6 KB
  const int t    = threadIdx.x;
  const int lane = t & 63;           // row slot within block
  const int w    = t >> 6;           // wave id = code chunk 0..7
  const unsigned nf = *nflag;

  for (unsigned g = blockIdx.x; g * 64u < nf; g += gridDim.x) {
    const unsigned ridx   = g * 64u + (unsigned)lane;
    const bool     active = ridx < nf;
    const int n  = (int)flaglist[active ? ridx : (nf - 1)];   // clamp: dummy row
    const int bb = n >> 10, hw = n & (HW - 1);

    __syncthreads();   // previous iteration's readers done before restage
    // stage x: thread (lane=row, w=8-channel slice); (lane*65+c)%32 -> no conflicts
    {
      const float* xb = xin + (size_t)bb * (CDIM * HW) + hw;
#pragma unroll
      for (int j = 0; j < 8; ++j)
        x_s[lane * XPAD + w * 8 + j] = xb[(size_t)(w * 8 + j) * HW];
    }
    __syncthreads();

    // per-lane register copy of its row
    float xr[CDIM];
#pragma unroll
    for (int c = 0; c < CDIM; ++c) xr[c] = x_s[lane * XPAD + c];
    const float S = np_sumsq64(xr);

    float dmin = INFINITY; int kmin = 0;
    const int kq = w * 128;
#pragma unroll 1
    for (int j = 0; j < 128; j += 2) {
      const int k0 = kq + j;                 // ascending k, pair (k0, k0+1)
      const int k1 = k0 + 1;
      const float4* e0 = (const float4*)(emb + (size_t)k0 * CDIM);  // wave-uniform
      const float4* e1 = (const float4*)(emb + (size_t)k1 * CDIM);
      float d0 = 0.0f, d1 = 0.0f;
#pragma unroll
      for (int c4 = 0; c4 < 16; ++c4) {      // exact reference chain, c ascending
        const float4 a0 = e0[c4];
        const float4 a1 = e1[c4];
        const float x0 = xr[4*c4+0], x1 = xr[4*c4+1];
        const float x2 = xr[4*c4+2], x3 = xr[4*c4+3];
        d0 = fmaf(x0, a0.x, d0); d1 = fmaf(x0, a1.x, d1);
        d0 = fmaf(x1, a0.y, d0); d1 = fmaf(x1, a1.y, d1);
        d0 = fmaf(x2, a0.z, d0); d1 = fmaf(x2, a1.z, d1);
        d0 = fmaf(x3, a0.w, d0); d1 = fmaf(x3, a1.w, d1);
      }
      const float q0 = (S - 2.0f * d0) + norms[k0];
      const float q1 = (S - 2.0f * d1) + norms[k1];
      if (q0 < dmin) { dmin = q0; kmin = k0; }   // strict < keeps first (lowest k)
      if (q1 < dmin) { dmin = q1; kmin = k1; }
    }

    if (active) {
      const float dc = dmin + 0.0f;              // -0.0 -> +0.0 canonicalization
      unsigned mb = __float_as_uint(dc);
      mb = (mb & 0x80000000u) ? ~mb : (mb | 0x80000000u);   // monotone total order
      pmin[(size_t)ridx * 8 + w] =
          ((unsigned long long)mb << 32) | (unsigned long long)(unsigned)kmin;
    }
  }
}

// Pass 2c: merge the 8 chunk-winners per flagged row (u64 min = lex (d,k) min).
__global__ void vq_resfin(const unsigned int* __restrict__ nflag,
                          const unsigned int* __restrict__ flaglist,
                          const unsigned long long* __restrict__ pmin,
                          float* __restrict__ out_idx)
{
  const unsigned nf = *nflag;
  for (unsigned i = blockIdx.x * blockDim.x + threadIdx.x; i < nf;
       i += gridDim.x * blockDim.x) {
    const unsigned long long* p = pmin + (size_t)i * 8;
    unsigned long long m = p[0];
#pragma unroll
    for (int j = 1; j < 8; ++j) { const unsigned long long v = p[j]; m = v < m ? v : m; }
    out_idx[flaglist[i]] = (float)(unsigned)(m & 1023u);
  }
}

// Pass 2a: epilogue for ALL rows — identical arithmetic & partials structure to the
// previously-passing kernel (1024 blocks x 64 rows, same shfl reduce order).
__global__ __launch_bounds__(64)
void vq_epilogue(const float* __restrict__ xin, const float* __restrict__ emb,
                 const float* __restrict__ out_idx, float* __restrict__ out0,
                 double* __restrict__ partials, unsigned int* __restrict__ counts)
{
  __shared__ unsigned int hist_s[NUM_K];
  const int t = threadIdx.x;
  const int n = blockIdx.x * 64 + t;
  for (int i = t; i < NUM_K; i += 64) hist_s[i] = 0;
  __syncthreads();
  const int bb = n >> 10, hw = n & (HW - 1);
  const float* xb = xin + (size_t)bb * (CDIM * HW) + hw;
  int kmin = (int)out_idx[n];
  if (kmin < 0) kmin = 0;                     // safety clamp (should not happen)
  atomicAdd(&hist_s[kmin], 1u);
  const float4* eb = (const float4*)(emb + (size_t)kmin * CDIM);
  float4* o = (float4*)(out0 + (size_t)n * CDIM);
  float ssq = 0.0f;
#pragma unroll
  for (int c4 = 0; c4 < 16; ++c4) {
    const float4 q4 = eb[c4];
    const float x0 = xb[(4*c4+0) * HW], x1 = xb[(4*c4+1) * HW];
    const float x2 = xb[(4*c4+2) * HW], x3 = xb[(4*c4+3) * HW];
    const float u0 = q4.x - x0, u1 = q4.y - x1, u2 = q4.z - x2, u3 = q4.w - x3;
    ssq = fmaf(u0, u0, fmaf(u1, u1, fmaf(u2, u2, fmaf(u3, u3, ssq))));
    o[c4] = make_float4(x0 + u0, x1 + u1, x2 + u2, x3 + u3);
  }
#pragma unroll
  for (int off = 32; off > 0; off >>= 1) ssq += __shfl_down(ssq, off, 64);
  if (t == 0) partials[blockIdx.x] = (double)ssq;   // deterministic, no FP atomics
  __syncthreads();
  for (int i = t; i < NUM_K; i += 64) {
    const unsigned int v = hist_s[i];
    if (v) atomicAdd(&counts[i], v);
  }
}

__global__ void vq_final(const double* __restrict__ partials,
                         const unsigned int* __restrict__ counts,
                         float* __restrict__ out_loss, float* __restrict__ out_perp)
{
  __shared__ double sh[256];
  const int t = threadIdx.x;
  double acc = 0.0, ent = 0.0;
  for (int i = t; i < NBLK; i += 256) acc += partials[i];
  for (int k = t; k < NUM_K; k += 256) {
    const double pr = (double)counts[k] * (1.0 / 65536.0);
    ent += pr * log(pr + 1e-10);
  }
  sh[t] = acc;
  __syncthreads();
  for (int s = 128; s > 0; s >>= 1) { if (t < s) sh[t] += sh[t + s]; __syncthreads(); }
  const double total = sh[0];
  __syncthreads();
  sh[t] = ent;
  __syncthreads();
  for (int s = 128; s > 0; s >>= 1) { if (t < s) sh[t] += sh[t + s]; __syncthreads(); }
  if (t == 0) {
    out_loss[0] = (float)(1.25 * total / 4194304.0);
    out_perp[0] = (float)exp(-sh[0]);
  }
}

extern "C" void kernel_launch(void* const* d_in, const int* in_sizes, int n_in,
                              void* d_out, int out_size, void* d_ws, size_t ws_size,
                              hipStream_t stream)
{
  const float* xin = (const float*)d_in[0];
  const float* emb = (const float*)d_in[1];
  float* out = (float*)d_out;

  // ws layout: [0,4K) fp32 norms[1024] | [4K,8K) u32 counts[1024] | [8K,16K) f64 partials[1024]
  float*        norms    = (float*)d_ws;
  unsigned int* counts   = (unsigned int*)((char*)d_ws + 4096);
  double*       partials = (double*)((char*)d_ws + 8192);

  float* out0     = out;                       // 4194304 elements (BHWC flat)
  float* out_loss = out + 4194304;             // scalar
  float* out_idx  = out + 4194305;             // 65536 elements (as float)
  float* out_perp = out + 4194305 + 65536;     // scalar

  // scratch stashed in out0 (consumed before vq_epilogue overwrites it):
  //   [0, 448K)           split codebook e' (1024 x 224 bf16)
  //   [8M, 8M+4)          u32 flag counter
  //   [8M+4, 8M+4+256K)   u32 flaglist (worst case 65536 rows)
  //   [10M, 14M)          u64 pmin[65536][8] chunk-winners (no init needed:
  //                       every read slot is written by vq_rescan)
  unsigned short*     esp      = (unsigned short*)out0;
  unsigned int*       nflag    = (unsigned int*)((char*)out0 + (8u << 20));
  unsigned int*       flaglist = nflag + 1;
  unsigned long long* pmin     = (unsigned long long*)((char*)out0 + (10u << 20));

  hipMemsetAsync((char*)d_ws + 4096, 0, 4096, stream);  // zero counts
  hipMemsetAsync(nflag, 0, 4, stream);                  // zero flag counter

  vq_prep    <<<dim3(16),   dim3(64),  0, stream>>>(emb, norms, esp);
  vq_dist    <<<dim3(1024), dim3(256), 0, stream>>>(xin, norms, esp, out_idx,
                                                    nflag, flaglist);
  vq_rescan  <<<dim3(128),  dim3(512), 0, stream>>>(xin, emb, norms, nflag,
                                                    flaglist, pmin);
  vq_resfin  <<<dim3(64),   dim3(256), 0, stream>>>(nflag, flaglist, pmin, out_idx);
  vq_epilogue<<<dim3(1024), dim3(64),  0, stream>>>(xin, emb, out_idx, out0, partials, counts);
  vq_final   <<<dim3(1),    dim3(256), 0, stream>>>(partials, counts, out_loss, out_perp);
}

// Round 8
// 217.616 us; speedup vs baseline: 1.3733x; 1.3733x over previous
//
#include <hip/hip_runtime.h>
#include <math.h>

#define NUM_K   1024
#define CDIM    64
#define HW      1024          // 32*32
#define NROWS   65536         // 64*1024
#define NBLK    1024          // epilogue blocks (64 rows each)
#define APAD    200           // A_s row stride in bf16 elems (400 B = 25*16B, odd -> bank-balanced)
#define BPAD    224           // esp row stride in bf16 elems (448 B, 64B-aligned fragments)
#define EPS_THR 1.25e-4f      // candidate threshold on packed g~ (incl. pack granularity)
#define XPAD    65            // rescan x_s row pad: (lane*65+c)%32 spreads banks (2/bank = free)

using bf16x8 = __attribute__((ext_vector_type(8))) short;
using f32x4  = __attribute__((ext_vector_type(4))) float;
using gcptr  = const __attribute__((address_space(1))) void*;
using lptr   = __attribute__((address_space(3))) void*;

// numpy pairwise_sum order for n=64 contiguous fp32 (8 stride-8 chains,
// ((r0+r1)+(r2+r3))+((r4+r5)+(r6+r7))), squares rounded separately (no FMA).
__device__ __forceinline__ float np_sumsq64(const float* a) {
#pragma clang fp contract(off)
  float r0 = a[0]*a[0], r1 = a[1]*a[1], r2 = a[2]*a[2], r3 = a[3]*a[3];
  float r4 = a[4]*a[4], r5 = a[5]*a[5], r6 = a[6]*a[6], r7 = a[7]*a[7];
#pragma unroll
  for (int i = 8; i < 64; i += 8) {
    r0 += a[i+0]*a[i+0]; r1 += a[i+1]*a[i+1];
    r2 += a[i+2]*a[i+2]; r3 += a[i+3]*a[i+3];
    r4 += a[i+4]*a[i+4]; r5 += a[i+5]*a[i+5];
    r6 += a[i+6]*a[i+6]; r7 += a[i+7]*a[i+7];
  }
  return ((r0+r1)+(r2+r3))+((r4+r5)+(r6+r7));
}

// Pass 0: exact norms + split codebook e' = [e_hi | e_hi | e_lo] (bf16 trunc split).
__global__ void vq_prep(const float* __restrict__ emb, float* __restrict__ norms,
                        unsigned short* __restrict__ esp)
{
  const int k = blockIdx.x * blockDim.x + threadIdx.x;
  if (k >= NUM_K) return;
  norms[k] = np_sumsq64(emb + k * CDIM);
  unsigned short* row = esp + (size_t)k * BPAD;
  for (int c = 0; c < CDIM; ++c) {
    const float v = emb[k * CDIM + c];
    const unsigned int vb = __float_as_uint(v);
    const unsigned short h = (unsigned short)(vb >> 16);           // bf16 trunc
    const float res = v - __uint_as_float((unsigned int)h << 16);
    const unsigned short l = (unsigned short)(__float_as_uint(res) >> 16);
    row[c] = h; row[64 + c] = h; row[128 + c] = l;
  }
  for (int i = 192; i < BPAD; ++i) row[i] = 0;
}

// Pass 1: split-bf16 MFMA distance filter (validated r1-r7, absmax 0). Unchanged.
__global__ __launch_bounds__(256, 2)
void vq_dist(const float* __restrict__ xin, const float* __restrict__ norms,
             const unsigned short* __restrict__ esp, float* __restrict__ out_idx,
             unsigned int* __restrict__ nflag, unsigned int* __restrict__ flaglist)
{
  __shared__ __align__(16) unsigned short A_s[64 * APAD];   // 25600 B
  __shared__ float red_m1[4][64];
  __shared__ float red_m2[4][64];

  const int t    = threadIdx.x;
  const int lane = t & 63;
  const int w    = t >> 6;        // wave id = 32-col slice of each 128-col chunk
  const int l15  = lane & 15;
  const int g4   = lane >> 4;

  const int n0  = blockIdx.x * 64;
  const int b   = n0 >> 10;
  const int hw0 = n0 & (HW - 1);

  // ---- stage A: load x (coalesced across rows), trunc-split, pack [hi|lo|hi] ----
  {
    const int r = t & 63, q = t >> 6;             // row, 16-channel quarter
    const float* xb = xin + (size_t)b * (CDIM * HW) + hw0 + r;
    unsigned short* arow = A_s + r * APAD;
#pragma unroll
    for (int u = 0; u < 8; ++u) {
      const int c0 = q * 16 + 2 * u;
      const float v0 = xb[(size_t)c0 * HW];
      const float v1 = xb[(size_t)(c0 + 1) * HW];
      const unsigned int h0 = __float_as_uint(v0) >> 16;
      const unsigned int h1 = __float_as_uint(v1) >> 16;
      const float r0 = v0 - __uint_as_float(h0 << 16);
      const float r1 = v1 - __uint_as_float(h1 << 16);
      const unsigned int lo0 = __float_as_uint(r0) >> 16;
      const unsigned int lo1 = __float_as_uint(r1) >> 16;
      const unsigned int hh = h0 | (h1 << 16);
      const unsigned int ll = lo0 | (lo1 << 16);
      *(unsigned int*)(arow + c0)        = hh;   // slots [0,64):   x_hi
      *(unsigned int*)(arow + 64 + c0)   = ll;   // slots [64,128): x_lo
      *(unsigned int*)(arow + 128 + c0)  = hh;   // slots [128,192):x_hi
    }
  }
  __syncthreads();

  float m1[16], m2[16];
#pragma unroll
  for (int i = 0; i < 16; ++i) { m1[i] = INFINITY; m2[i] = INFINITY; }

  // per-lane A fragment base (bf16 elems); rt adds 16*APAD, s adds 32
  const unsigned short* aF = A_s + l15 * APAD + g4 * 8;
  // per-lane B pointers for (ct0, ct1); s adds 32, chunk adds 128*BPAD
  const unsigned short* pB = esp + (size_t)(w * 32 + l15) * BPAD + g4 * 8;
  const float* pN = norms + w * 32 + l15;

  // preloaded s=0 fragments of the current chunk (carried across iterations;
  // last iteration's extra preload reads harmless in-bounds garbage past esp)
  bf16x8 c0 = *(const bf16x8*)(pB);
  bf16x8 c1 = *(const bf16x8*)(pB + 16 * BPAD);

#pragma unroll 1
  for (int cb = 0; cb < 8; ++cb) {
    const float nk0 = pN[0];
    const float nk1 = pN[16];

    f32x4 acc[4][2];
#pragma unroll
    for (int rt = 0; rt < 4; ++rt)
#pragma unroll
      for (int ct = 0; ct < 2; ++ct)
        acc[rt][ct] = (f32x4){0.0f, 0.0f, 0.0f, 0.0f};

    // s = 0 uses the preloaded pair
    {
      const bf16x8 a0 = *(const bf16x8*)(aF);
      const bf16x8 a1 = *(const bf16x8*)(aF + 16 * APAD);
      const bf16x8 a2 = *(const bf16x8*)(aF + 32 * APAD);
      const bf16x8 a3 = *(const bf16x8*)(aF + 48 * APAD);
      acc[0][0] = __builtin_amdgcn_mfma_f32_16x16x32_bf16(a0, c0, acc[0][0], 0, 0, 0);
      acc[1][0] = __builtin_amdgcn_mfma_f32_16x16x32_bf16(a1, c0, acc[1][0], 0, 0, 0);
      acc[2][0] = __builtin_amdgcn_mfma_f32_16x16x32_bf16(a2, c0, acc[2][0], 0, 0, 0);
      acc[3][0] = __builtin_amdgcn_mfma_f32_16x16x32_bf16(a3, c0, acc[3][0], 0, 0, 0);
      acc[0][1] = __builtin_amdgcn_mfma_f32_16x16x32_bf16(a0, c1, acc[0][1], 0, 0, 0);
      acc[1][1] = __builtin_amdgcn_mfma_f32_16x16x32_bf16(a1, c1, acc[1][1], 0, 0, 0);
      acc[2][1] = __builtin_amdgcn_mfma_f32_16x16x32_bf16(a2, c1, acc[2][1], 0, 0, 0);
      acc[3][1] = __builtin_amdgcn_mfma_f32_16x16x32_bf16(a3, c1, acc[3][1], 0, 0, 0);
    }
#pragma unroll
    for (int s = 1; s < 6; ++s) {
      const bf16x8 b0 = *(const bf16x8*)(pB + s * 32);
      const bf16x8 b1 = *(const bf16x8*)(pB + 16 * BPAD + s * 32);
      const bf16x8 a0 = *(const bf16x8*)(aF + s * 32);
      const bf16x8 a1 = *(const bf16x8*)(aF + 16 * APAD + s * 32);
      const bf16x8 a2 = *(const bf16x8*)(aF + 32 * APAD + s * 32);
      const bf16x8 a3 = *(const bf16x8*)(aF + 48 * APAD + s * 32);
      acc[0][0] = __builtin_amdgcn_mfma_f32_16x16x32_bf16(a0, b0, acc[0][0], 0, 0, 0);
      acc[1][0] = __builtin_amdgcn_mfma_f32_16x16x32_bf16(a1, b0, acc[1][0], 0, 0, 0);
      acc[2][0] = __builtin_amdgcn_mfma_f32_16x16x32_bf16(a2, b0, acc[2][0], 0, 0, 0);
      acc[3][0] = __builtin_amdgcn_mfma_f32_16x16x32_bf16(a3, b0, acc[3][0], 0, 0, 0);
      acc[0][1] = __builtin_amdgcn_mfma_f32_16x16x32_bf16(a0, b1, acc[0][1], 0, 0, 0);
      acc[1][1] = __builtin_amdgcn_mfma_f32_16x16x32_bf16(a1, b1, acc[1][1], 0, 0, 0);
      acc[2][1] = __builtin_amdgcn_mfma_f32_16x16x32_bf16(a2, b1, acc[2][1], 0, 0, 0);
      acc[3][1] = __builtin_amdgcn_mfma_f32_16x16x32_bf16(a3, b1, acc[3][1], 0, 0, 0);
    }

    const unsigned kbase = (unsigned)(cb * 128 + w * 32 + l15);
    pB += 128 * BPAD;
    pN += 128;
    // preload next chunk's s=0 pair; hides L2 latency under the epilogue VALU
    c0 = *(const bf16x8*)(pB);
    c1 = *(const bf16x8*)(pB + 16 * BPAD);

    // epilogue: g~ = nk - 2*dot~, pack col idx into low 10 mantissa bits, fminf-track.
#pragma unroll
    for (int ct = 0; ct < 2; ++ct) {
      const float nk = ct ? nk1 : nk0;
      const unsigned kcol = kbase + (unsigned)(ct * 16);
#pragma unroll
      for (int rt = 0; rt < 4; ++rt) {
#pragma unroll
        for (int rg = 0; rg < 4; ++rg) {
          const float g  = fmaf(-2.0f, acc[rt][ct][rg], nk);
          const float gp = __uint_as_float((__float_as_uint(g) & 0xFFFFFC00u) | kcol);
          const int   si = rt * 4 + rg;
          m2[si] = fminf(m2[si], fmaxf(m1[si], gp));
          m1[si] = fminf(m1[si], gp);
        }
      }
    }
  }

  // butterfly merge across the 16 col-lanes (packed: no index shuffles needed)
#pragma unroll
  for (int mask = 1; mask <= 8; mask <<= 1) {
#pragma unroll
    for (int si = 0; si < 16; ++si) {
      const float om1 = __shfl_xor(m1[si], mask, 64);
      const float om2 = __shfl_xor(m2[si], mask, 64);
      m2[si] = fminf(fminf(m2[si], om2), fmaxf(m1[si], om1));
      m1[si] = fminf(m1[si], om1);
    }
  }
  if (l15 == 0) {
#pragma unroll
    for (int rt = 0; rt < 4; ++rt)
#pragma unroll
      for (int rg = 0; rg < 4; ++rg) {
        const int row = rt * 16 + g4 * 4 + rg;
        red_m1[w][row] = m1[rt * 4 + rg];
        red_m2[w][row] = m2[rt * 4 + rg];
      }
  }
  __syncthreads();
  if (t < 64) {
    float M1 = red_m1[0][t], M2 = red_m2[0][t];
#pragma unroll
    for (int ww = 1; ww < 4; ++ww) {
      const float om1 = red_m1[ww][t], om2 = red_m2[ww][t];
      M2 = fminf(fminf(M2, om2), fmaxf(M1, om1));
      M1 = fminf(M1, om1);
    }
    const int K1 = (int)(__float_as_uint(M1) & 1023u);
    out_idx[n0 + t] = (float)K1;     // best guess; flagged rows fixed by rescan
    if (M2 - M1 <= EPS_THR) {        // gap too small -> exact rescan required
      const unsigned pos = atomicAdd(nflag, 1u);
      flaglist[pos] = (unsigned)(n0 + t);
    }
  }
}

// Pass 2b: exact rescan v6 — LDS codes + lane=row, 1 wave/block (r8 rewrite).
// r5/r6/r7 post-mortem: xr[64] consumed the VGPR budget (VGPR_Count 64-80), so
// per-pair e-loads from L2 could not pipeline -> ~200cy serial round trips ->
// fixed ~110-150us regardless of decomposition. Fix: codes come from LDS
// (latency off the critical path), staged 32KB/chunk via global_load_lds
// (zero VGPR cost); launch_bounds(64,1) lifts the reg cap so xr[64] stays in
// VGPRs. Task = (64-row group g, 128-code chunk c); lane = row; the wave walks
// its chunk wave-uniform (broadcast ds_read, conflict-free); dual-code FMA
// chains -> issue-bound. Each lane owns its row for the chunk -> winner written
// directly to pmin[ridx*8+c] (validated monotone u64 pack; u64-min merge = lex
// (d,k) first-min). Exact chain semantics unchanged from r4-r7 (absmax 0).
__global__ __launch_bounds__(64, 1)
void vq_rescan(const float* __restrict__ xin, const float* __restrict__ emb,
               const float* __restrict__ norms,
               const unsigned int* __restrict__ nflag,
               const unsigned int* __restrict__ flaglist,
               unsigned long long* __restrict__ pmin)
{
  __shared__ __align__(16) float e_s[128 * CDIM];   // 32 KB, linear (gll dest)
  __shared__ float nk_s[128];                       // 512 B
  __shared__ float x_s[64 * XPAD];                  // 16.6 KB
  const int lane = threadIdx.x & 63;
  const unsigned nf = *nflag;
  const unsigned T  = ((nf + 63) >> 6) * 8u;        // (group, chunk) tasks

  for (unsigned tau = blockIdx.x; tau < T; tau += gridDim.x) {
    const unsigned g = tau >> 3;
    const int      c = (int)(tau & 7);              // code chunk

    __syncthreads();   // prior iteration's LDS readers done before restage

    // stage 128 codes (32 KB): 32 wave-uniform-dest global_load_lds issues,
    // all in flight, no VGPR cost
    {
      const char* src = (const char*)(emb + (size_t)c * 128 * CDIM);
#pragma unroll
      for (int i = 0; i < 32; ++i)
        __builtin_amdgcn_global_load_lds(
            (gcptr)(src + (size_t)i * 1024 + (size_t)lane * 16),
            (lptr)((char*)e_s + (size_t)i * 1024), 16, 0, 0);
    }
    // stage this chunk's norms (wave-uniform dest, 2 issues of 4B)
    {
      const char* nsrc = (const char*)(norms + c * 128);
      __builtin_amdgcn_global_load_lds((gcptr)(nsrc + (size_t)lane * 4),
                                       (lptr)(char*)nk_s, 4, 0, 0);
      __builtin_amdgcn_global_load_lds((gcptr)(nsrc + 256 + (size_t)lane * 4),
                                       (lptr)((char*)nk_s + 256), 4, 0, 0);
    }

    // stage x rows: row r's id broadcast via shfl; lane = channel (coalesced
    // across nothing -- BHWC gather, but loads are independent -> pipelined)
    const unsigned ridx   = g * 64u + (unsigned)lane;
    const bool     active = ridx < nf;
    const int nlane = (int)flaglist[active ? ridx : (nf - 1)];
#pragma unroll 4
    for (int r = 0; r < 64; ++r) {
      const int nr = __shfl(nlane, r, 64);
      const int bb = nr >> 10, hw = nr & (HW - 1);
      x_s[r * XPAD + lane] = xin[(size_t)bb * (CDIM * HW) + (size_t)lane * HW + hw];
    }
    __syncthreads();   // drains global_load_lds (vmcnt) + ds writes

    // per-lane register copy of its row; (lane*65+c)%32 -> 2 lanes/bank = free
    float xr[CDIM];
#pragma unroll
    for (int cc = 0; cc < CDIM; ++cc) xr[cc] = x_s[lane * XPAD + cc];
    const float S = np_sumsq64(xr);

    float dmin = INFINITY; int kmin = 0;
#pragma unroll 2
    for (int j = 0; j < 128; j += 2) {
      const float* e0 = e_s + j * CDIM;        // wave-uniform LDS reads (broadcast)
      const float* e1 = e0 + CDIM;
      float d0 = 0.0f, d1 = 0.0f;
#pragma unroll
      for (int c4 = 0; c4 < 16; ++c4) {        // exact reference chain, c ascending
        const float4 a0 = *(const float4*)(e0 + 4 * c4);
        const float4 a1 = *(const float4*)(e1 + 4 * c4);
        const float x0 = xr[4*c4+0], x1 = xr[4*c4+1];
        const float x2 = xr[4*c4+2], x3 = xr[4*c4+3];
        d0 = fmaf(x0, a0.x, d0); d1 = fmaf(x0, a1.x, d1);
        d0 = fmaf(x1, a0.y, d0); d1 = fmaf(x1, a1.y, d1);
        d0 = fmaf(x2, a0.z, d0); d1 = fmaf(x2, a1.z, d1);
        d0 = fmaf(x3, a0.w, d0); d1 = fmaf(x3, a1.w, d1);
      }
      const int k0 = c * 128 + j;              // ascending k
      const float q0 = (S - 2.0f * d0) + nk_s[j];
      const float q1 = (S - 2.0f * d1) + nk_s[j + 1];
      if (q0 < dmin) { dmin = q0; kmin = k0; }     // strict < keeps first (lowest k)
      if (q1 < dmin) { dmin = q1; kmin = k0 + 1; }
    }

    if (active) {
      const float dc = dmin + 0.0f;              // -0.0 -> +0.0 canonicalization
      unsigned mb = __float_as_uint(dc);
      mb = (mb & 0x80000000u) ? ~mb : (mb | 0x80000000u);   // monotone total order
      pmin[(size_t)ridx * 8 + c] =
          ((unsigned long long)mb << 32) | (unsigned long long)(unsigned)kmin;
    }
  }
}

// Pass 2c: merge the 8 chunk-winners per flagged row (u64 min = lex (d,k) min).
__global__ void vq_resfin(const unsigned int* __restrict__ nflag,
                          const unsigned int* __restrict__ flaglist,
                          const unsigned long long* __restrict__ pmin,
                          float* __restrict__ out_idx)
{
  const unsigned nf = *nflag;
  for (unsigned i = blockIdx.x * blockDim.x + threadIdx.x; i < nf;
       i += gridDim.x * blockDim.x) {
    const unsigned long long* p = pmin + (size_t)i * 8;
    unsigned long long m = p[0];
#pragma unroll
    for (int j = 1; j < 8; ++j) { const unsigned long long v = p[j]; m = v < m ? v : m; }
    out_idx[flaglist[i]] = (float)(unsigned)(m & 1023u);
  }
}

// Pass 2a: epilogue for ALL rows — identical arithmetic & partials structure to the
// previously-passing kernel (1024 blocks x 64 rows, same shfl reduce order).
__global__ __launch_bounds__(64)
void vq_epilogue(const float* __restrict__ xin, const float* __restrict__ emb,
                 const float* __restrict__ out_idx, float* __restrict__ out0,
                 double* __restrict__ partials, unsigned int* __restrict__ counts)
{
  __shared__ unsigned int hist_s[NUM_K];
  const int t = threadIdx.x;
  const int n = blockIdx.x * 64 + t;
  for (int i = t; i < NUM_K; i += 64) hist_s[i] = 0;
  __syncthreads();
  const int bb = n >> 10, hw = n & (HW - 1);
  const float* xb = xin + (size_t)bb * (CDIM * HW) + hw;
  int kmin = (int)out_idx[n];
  if (kmin < 0) kmin = 0;                     // safety clamp (should not happen)
  atomicAdd(&hist_s[kmin], 1u);
  const float4* eb = (const float4*)(emb + (size_t)kmin * CDIM);
  float4* o = (float4*)(out0 + (size_t)n * CDIM);
  float ssq = 0.0f;
#pragma unroll
  for (int c4 = 0; c4 < 16; ++c4) {
    const float4 q4 = eb[c4];
    const float x0 = xb[(4*c4+0) * HW], x1 = xb[(4*c4+1) * HW];
    const float x2 = xb[(4*c4+2) * HW], x3 = xb[(4*c4+3) * HW];
    const float u0 = q4.x - x0, u1 = q4.y - x1, u2 = q4.z - x2, u3 = q4.w - x3;
    ssq = fmaf(u0, u0, fmaf(u1, u1, fmaf(u2, u2, fmaf(u3, u3, ssq))));
    o[c4] = make_float4(x0 + u0, x1 + u1, x2 + u2, x3 + u3);
  }
#pragma unroll
  for (int off = 32; off > 0; off >>= 1) ssq += __shfl_down(ssq, off, 64);
  if (t == 0) partials[blockIdx.x] = (double)ssq;   // deterministic, no FP atomics
  __syncthreads();
  for (int i = t; i < NUM_K; i += 64) {
    const unsigned int v = hist_s[i];
    if (v) atomicAdd(&counts[i], v);
  }
}

__global__ void vq_final(const double* __restrict__ partials,
                         const unsigned int* __restrict__ counts,
                         float* __restrict__ out_loss, float* __restrict__ out_perp)
{
  __shared__ double sh[256];
  const int t = threadIdx.x;
  double acc = 0.0, ent = 0.0;
  for (int i = t; i < NBLK; i += 256) acc += partials[i];
  for (int k = t; k < NUM_K; k += 256) {
    const double pr = (double)counts[k] * (1.0 / 65536.0);
    ent += pr * log(pr + 1e-10);
  }
  sh[t] = acc;
  __syncthreads();
  for (int s = 128; s > 0; s >>= 1) { if (t < s) sh[t] += sh[t + s]; __syncthreads(); }
  const double total = sh[0];
  __syncthreads();
  sh[t] = ent;
  __syncthreads();
  for (int s = 128; s > 0; s >>= 1) { if (t < s) sh[t] += sh[t + s]; __syncthreads(); }
  if (t == 0) {
    out_loss[0] = (float)(1.25 * total / 4194304.0);
    out_perp[0] = (float)exp(-sh[0]);
  }
}

extern "C" void kernel_launch(void* const* d_in, const int* in_sizes, int n_in,
                              void* d_out, int out_size, void* d_ws, size_t ws_size,
                              hipStream_t stream)
{
  const float* xin = (const float*)d_in[0];
  const float* emb = (const float*)d_in[1];
  float* out = (float*)d_out;

  // ws layout: [0,4K) fp32 norms[1024] | [4K,8K) u32 counts[1024] | [8K,16K) f64 partials[1024]
  float*        norms    = (float*)d_ws;
  unsigned int* counts   = (unsigned int*)((char*)d_ws + 4096);
  double*       partials = (double*)((char*)d_ws + 8192);

  float* out0     = out;                       // 4194304 elements (BHWC flat)
  float* out_loss = out + 4194304;             // scalar
  float* out_idx  = out + 4194305;             // 65536 elements (as float)
  float* out_perp = out + 4194305 + 65536;     // scalar

  // scratch stashed in out0 (consumed before vq_epilogue overwrites it):
  //   [0, 448K)           split codebook e' (1024 x 224 bf16)
  //   [8M, 8M+4)          u32 flag counter
  //   [8M+4, 8M+4+256K)   u32 flaglist (worst case 65536 rows)
  //   [10M, 14M)          u64 pmin[65536][8] chunk-winners (no init needed:
  //                       every read slot is written by vq_rescan)
  unsigned short*     esp      = (unsigned short*)out0;
  unsigned int*       nflag    = (unsigned int*)((char*)out0 + (8u << 20));
  unsigned int*       flaglist = nflag + 1;
  unsigned long long* pmin     = (unsigned long long*)((char*)out0 + (10u << 20));

  hipMemsetAsync((char*)d_ws + 4096, 0, 4096, stream);  // zero counts
  hipMemsetAsync(nflag, 0, 4, stream);                  // zero flag counter

  vq_prep    <<<dim3(16),   dim3(64),  0, stream>>>(emb, norms, esp);
  vq_dist    <<<dim3(1024), dim3(256), 0, stream>>>(xin, norms, esp, out_idx,
                                                    nflag, flaglist);
  vq_rescan  <<<dim3(1024), dim3(64),  0, stream>>>(xin, emb, norms, nflag,
                                                    flaglist, pmin);
  vq_resfin  <<<dim3(64),   dim3(256), 0, stream>>>(nflag, flaglist, pmin, out_idx);
  vq_epilogue<<<dim3(1024), dim3(64),  0, stream>>>(xin, emb, out_idx, out0, partials, counts);
  vq_final   <<<dim3(1),    dim3(256), 0, stream>>>(partials, counts, out_loss, out_perp);
}